// Round 7
// baseline (231.798 us; speedup 1.0000x reference)
//
#include <hip/hip_runtime.h>
#include <math.h>

#define NN 50000
#define NE 800000
#define D_IN 64
#define D_HID 256
#define BN_EPS 1e-5f
#define ZSTR 264   // LDS tile row stride in shorts (+8 pad: 16B-aligned rows, spread banks)
#define SB 128     // k_stats grid blocks
#define BCAP 64    // CSR bucket capacity per node (Poisson(16): P(deg>=64) ~ 1e-18)
#define BINCAP 8192 // edges per 256-node bin (mean 4081, 64 sigma headroom)

typedef __attribute__((ext_vector_type(8))) short short8;
typedef __attribute__((ext_vector_type(4))) float f32x4;
typedef __attribute__((ext_vector_type(4))) int int4v;      // ext-vector: nontemporal-legal
typedef __attribute__((ext_vector_type(4))) float float4v;  // ext-vector: nontemporal-legal

static __device__ __forceinline__ unsigned short f2bf(float f) {
    unsigned int u = __builtin_bit_cast(unsigned int, f);
    u += 0x7FFFu + ((u >> 16) & 1u);   // round-to-nearest-even
    return (unsigned short)(u >> 16);
}
static __device__ __forceinline__ float bf2f(unsigned short s) {
    unsigned int u = ((unsigned int)s) << 16;
    return __builtin_bit_cast(float, u);
}
// fast sigmoid: rcp(1+e^-x). Saturates cleanly at +/-inf, no NaN.
static __device__ __forceinline__ float fast_sigmoid(float x) {
    return __builtin_amdgcn_rcpf(1.0f + __expf(-x));
}
// fast tanh: 1 - 2*rcp(e^{2x}+1). Saturates cleanly, no NaN.
static __device__ __forceinline__ float fast_tanh(float x) {
    return 1.0f - 2.0f * __builtin_amdgcn_rcpf(__expf(2.0f * x) + 1.0f);
}

// A-frag-linear address for element (row i, feature k):
// ((i>>4)*2 + (k>>5))*512 + (((k>>3)&3)*16 + (i&15))*8 + (k&7)
static __device__ __forceinline__ long a_addr(int i, int k) {
    return ((long)((i >> 4) * 2 + (k >> 5)) << 9) + ((((k >> 3) & 3) * 16 + (i & 15)) << 3) + (k & 7);
}

// ---------------- pre: pack weights + PHASE-A edge binning ------------------------------
// Bin edges by dst>>8 into contiguous per-bin chunks (LDS count -> one global cursor
// atomicAdd per (block,bin) -> ~84B contiguous chunk writes). eidx loads non-temporal
// (read-once stream; don't churn L2).
__global__ __launch_bounds__(256) void k_pre(const float* __restrict__ W_gcn,
                      const float* __restrict__ W_lin, const float* __restrict__ W_gate,
                      unsigned short* __restrict__ Wp_gcn, unsigned short* __restrict__ Wp_lin,
                      unsigned short* __restrict__ Wp_gate,
                      const int* __restrict__ eidx, int* __restrict__ bincur,
                      unsigned int* __restrict__ binbuf, int E) {
    int idx = blockIdx.x * blockDim.x + threadIdx.x;
    if (idx < 98304) {
        const float* W;
        unsigned short* Wp;
        int KC, o;
        if (idx < 16384)      { W = W_gcn;  Wp = Wp_gcn;  KC = 2; o = idx; }
        else if (idx < 32768) { W = W_lin;  Wp = Wp_lin;  KC = 2; o = idx - 16384; }
        else                  { W = W_gate; Wp = Wp_gate; KC = 8; o = idx - 32768; }
        int j = o & 7;
        int lane = (o >> 3) & 63;
        int rest = o >> 9;
        int kc = rest % KC;
        int ct = rest / KC;
        int col = ct * 16 + (lane & 15);
        int k = kc * 32 + (lane >> 4) * 8 + j;
        Wp[o] = f2bf(W[k * D_HID + col]);
    }

    // ---- phase A binning: blocks 0..nbb-1, 4096 edges each ----
    int b = blockIdx.x;
    int t = threadIdx.x;
    int nbb = (E + 4095) >> 12;
    if (b < nbb) {
        __shared__ int bcnt[256];
        __shared__ int gbase[256];
        bcnt[t] = 0;
        __syncthreads();
        unsigned int pair[4][4];
        int bin[4][4], lr[4][4];
        bool val[4];
#pragma unroll
        for (int c = 0; c < 4; c++) {
            int e0 = b * 4096 + c * 1024 + t * 4;
            val[c] = e0 < E;
            if (val[c]) {
                int4v s = __builtin_nontemporal_load((const int4v*)(eidx + e0));
                int4v d = __builtin_nontemporal_load((const int4v*)(eidx + E + e0));
                int ss[4] = {s[0], s[1], s[2], s[3]};
                int dd[4] = {d[0], d[1], d[2], d[3]};
#pragma unroll
                for (int j = 0; j < 4; j++) {
                    int bi = dd[j] >> 8;
                    bin[c][j] = bi;
                    pair[c][j] = ((unsigned int)(dd[j] & 255) << 16) | (unsigned int)ss[j];
                    lr[c][j] = atomicAdd(&bcnt[bi], 1);
                }
            }
        }
        __syncthreads();
        if (bcnt[t] > 0) gbase[t] = atomicAdd(&bincur[t], bcnt[t]);
        __syncthreads();
#pragma unroll
        for (int c = 0; c < 4; c++)
            if (val[c]) {
#pragma unroll
                for (int j = 0; j < 4; j++) {
                    int slot = gbase[bin[c][j]] + lr[c][j];
                    if (slot < BINCAP)
                        binbuf[((long)bin[c][j] << 13) + slot] = pair[c][j];
                }
            }
    }
}

// ---------------- binfill: PHASE-B per-bin CSR built in LDS, written coalesced ----------
__global__ __launch_bounds__(256) void k_binfill(const unsigned int* __restrict__ binbuf,
                      const int* __restrict__ bincur,
                      unsigned short* __restrict__ csr, int* __restrict__ cnt, int n) {
    __shared__ unsigned short buck[256 * BCAP];   // 32KB
    __shared__ int lcnt[256];
    int b = blockIdx.x;
    int t = threadIdx.x;
    lcnt[t] = 0;
    __syncthreads();
    int tot = bincur[b];
    tot = tot < BINCAP ? tot : BINCAP;
    for (int i = t; i < tot; i += 256) {
        unsigned int p = binbuf[((long)b << 13) + i];
        int dl = p >> 16;
        int src = p & 0xFFFF;
        int r = atomicAdd(&lcnt[dl], 1);
        if (r < BCAP) buck[dl * BCAP + r] = (unsigned short)src;
    }
    __syncthreads();
    int node0 = b << 8;
    if (node0 + t < n) cnt[node0 + t] = lcnt[t];   // true degree (gather clamps to BCAP)
    // 2048 short8 rows -> 8 per thread, fully coalesced
#pragma unroll
    for (int v = 0; v < 8; v++) {
        int e = (v * 256 + t) * 8;      // short index into buck
        int node = e >> 6;
        if (node0 + node < n)
            *(short8*)(csr + ((long)(node0 + node) << 6) + (e & 63)) = *(const short8*)(&buck[e]);
    }
}

// ---------------- prep: dinv + bf16 feature packing (PLANE-SPLIT xscaled) ---------------
// xscaled stored as TWO 3.2MB planes xpl[p][(n+1)][32] (features p*32..). The gather's
// random-reuse working set was 6.4MB > 4MiB per-XCD L2 -> L3 latency on ~half the row
// reads. Each 3.2MB plane IS L2-resident during its own gather pass.
__global__ __launch_bounds__(256) void k_prep(const float* __restrict__ xs,
                           const int* __restrict__ cnt,
                           float* __restrict__ dinv, unsigned short* __restrict__ xpl,
                           unsigned short* __restrict__ xs_p, int n) {
    long PS = (long)(n + 1) * 32;       // plane stride in shorts
    int idx = blockIdx.x * blockDim.x + threadIdx.x;
    if (idx >= n * 8) {
        if (idx < n * 8 + 8) {  // zero sentinel row n in both planes (gather tail clamp)
            int sub = idx - n * 8;
            short8 zv = (short8){0, 0, 0, 0, 0, 0, 0, 0};
            *(short8*)(xpl + (long)(sub >> 2) * PS + (long)n * 32 + (sub & 3) * 8) = zv;
        }
        return;
    }
    int i = idx >> 3;
    int sub = idx & 7;
    float dv = rsqrtf(1.0f + (float)cnt[i]);
    if (sub == 0) dinv[i] = dv;
    const float* p = xs + (long)i * D_IN + sub * 8;
    float4v f0 = __builtin_nontemporal_load((const float4v*)p);
    float4v f1 = __builtin_nontemporal_load((const float4v*)(p + 4));
    float vals[8] = {f0[0], f0[1], f0[2], f0[3], f1[0], f1[1], f1[2], f1[3]};
    short8 xsc, xsb;
#pragma unroll
    for (int j = 0; j < 8; j++) {
        xsc[j] = (short)f2bf(vals[j] * dv);
        xsb[j] = (short)f2bf(vals[j]);
    }
    *(short8*)(xpl + (long)(sub >> 2) * PS + (long)i * 32 + (sub & 3) * 8) = xsc;
    *(short8*)(xs_p + a_addr(i, sub * 8)) = xsb;
}

// ---------------- gather pass p: wave per node, 16 rows x 16B/lane-quad per round -------
// One dispatch per plane: the pass's random-read set (3.2MB plane) fits per-XCD L2.
// csr loads are non-temporal (streamed once per pass; don't evict the plane).
__global__ __launch_bounds__(256) void k_gather(const unsigned short* __restrict__ csr,
                                                const int* __restrict__ cnt,
                                                const unsigned short* __restrict__ xpl_p,
                                                const float* __restrict__ dinv,
                                                unsigned short* __restrict__ agg_p,
                                                int n, int p) {
    int wv = threadIdx.x >> 6;
    int lane = threadIdx.x & 63;
    int sub = lane & 3;       // feature octet within plane (8 bf16 = 16B)
    int grp = lane >> 2;      // 16 rows in parallel per round
    int i = blockIdx.x * 4 + wv;
    if (i >= n) return;
    int c = cnt[i];
    c = c < BCAP ? c : BCAP;            // bucket clamp (never hit for this data)
    float acc[8];
#pragma unroll
    for (int j = 0; j < 8; j++) acc[j] = 0.f;
    int idxv = (lane < c) ? (int)__builtin_nontemporal_load(csr + ((long)i << 6) + lane) : 0;
    int tmax = (c + 15) >> 4;           // wave-uniform trip count (deg~16 -> 1 round)
    for (int t = 0; t < tmax; t++) {
        int e = t * 16 + grp;
        int rowv = __shfl(idxv, e);
        int row = (e < c) ? rowv : n;   // clamp tail to zero sentinel row
        short8 v = *(const short8*)(xpl_p + (long)row * 32 + sub * 8);
#pragma unroll
        for (int j = 0; j < 8; j++) acc[j] += bf2f((unsigned short)v[j]);
    }
#pragma unroll
    for (int d = 4; d <= 32; d <<= 1)
#pragma unroll
        for (int j = 0; j < 8; j++) acc[j] += __shfl_xor(acc[j], d);
    if (lane < 4) {                     // lanes 0..3 hold totals for sub=0..3
        float dv = dinv[i];
        short8 sv = *(const short8*)(xpl_p + (long)i * 32 + sub * 8);  // self loop
        short8 o;
#pragma unroll
        for (int j = 0; j < 8; j++)
            o[j] = (short)f2bf((acc[j] + bf2f((unsigned short)sv[j])) * dv);
        // a_addr(i, p*32 + sub*8): chunk ((i>>4)*2+p), offset (sub*16 + (i&15))*8
        *(short8*)(agg_p + ((long)((i >> 4) * 2 + p) << 9) + (sub * 16 + (i & 15)) * 8) = o;
    }
}

// ---------------- fused v6: TLP-focused -------------------------------------------------
//   (a) 32-row blocks: grid 1564, LDS 16.9 KB
//   (b) __launch_bounds__(256,4): VGPR cap 128 -> 4 waves/SIMD
//   (c) A-tiles (agg, xs) prefetched into registers at kernel entry
__global__ __launch_bounds__(256, 4) void k_fused(const unsigned short* __restrict__ agg_p,
                        const unsigned short* __restrict__ xs_p,
                        const unsigned short* __restrict__ Wp_gcn,
                        const unsigned short* __restrict__ Wp_lin,
                        const unsigned short* __restrict__ Wp_gate,
                        const float* __restrict__ b_gcn,
                        const float* __restrict__ bg,
                        const float* __restrict__ bl,
                        unsigned short* __restrict__ out_pre,  // [npad][256]
                        int n) {
    __shared__ unsigned short z_lds[32 * ZSTR];   // 16.9 KB (z, then o in-place)

    int tid = threadIdx.x;
    int wv = tid >> 6;
    int lane = tid & 63;
    int l15 = lane & 15;
    int quad = lane >> 4;
    int rt0 = blockIdx.x * 2;           // 2 row-tiles of 16 per block

    // ---- prefetch both A-operand tiles into registers (issued before anything else) ----
    short8 aggf[2][2], xsf[2][2];
#pragma unroll
    for (int r = 0; r < 2; r++)
#pragma unroll
        for (int kc = 0; kc < 2; kc++) {
            aggf[r][kc] = *(const short8*)(agg_p + ((long)((rt0 + r) * 2 + kc) << 9) + lane * 8);
            xsf[r][kc]  = *(const short8*)(xs_p  + ((long)((rt0 + r) * 2 + kc) << 9) + lane * 8);
        }

    // ---- phase A: z = tanh(agg @ W_gcn + b), K=64 ----
    {
        short8 wg[2][4];
#pragma unroll
        for (int kc = 0; kc < 2; kc++)
#pragma unroll
            for (int tn = 0; tn < 4; tn++)
                wg[kc][tn] = *(const short8*)(Wp_gcn + ((long)((wv * 4 + tn) * 2 + kc) << 9) + lane * 8);
        float bias[4];
#pragma unroll
        for (int tn = 0; tn < 4; tn++) bias[tn] = b_gcn[wv * 64 + tn * 16 + l15];
#pragma unroll
        for (int r = 0; r < 2; r++) {
            f32x4 accz[4];
#pragma unroll
            for (int c = 0; c < 4; c++) accz[c] = (f32x4){0.f, 0.f, 0.f, 0.f};
#pragma unroll
            for (int kc = 0; kc < 2; kc++)
#pragma unroll
                for (int tn = 0; tn < 4; tn++)
                    accz[tn] = __builtin_amdgcn_mfma_f32_16x16x32_bf16(aggf[r][kc], wg[kc][tn], accz[tn], 0, 0, 0);
#pragma unroll
            for (int tn = 0; tn < 4; tn++) {
                int col = wv * 64 + tn * 16 + l15;
#pragma unroll
                for (int r2 = 0; r2 < 4; r2++)
                    z_lds[(r * 16 + quad * 4 + r2) * ZSTR + col] = f2bf(fast_tanh(accz[tn][r2] + bias[tn]));
            }
        }
    }
    __syncthreads();

    // ---- phase B per tn-pair: xl GEMM (A in regs) -> gate GEMM -> epilogue ----
    uint2 o_pk[2][4];
    float bgc[4], blc[4];
#pragma unroll
    for (int tn = 0; tn < 4; tn++) {
        int col = wv * 64 + tn * 16 + l15;
        bgc[tn] = bg[col];
        blc[tn] = bl[col];
    }
#pragma unroll
    for (int tnp = 0; tnp < 2; tnp++) {
        // B1: xl = xs @ W_lin, K=64, A-frags already in registers
        f32x4 accl[2][2];
#pragma unroll
        for (int r = 0; r < 2; r++)
#pragma unroll
            for (int h = 0; h < 2; h++) accl[r][h] = (f32x4){0.f, 0.f, 0.f, 0.f};
#pragma unroll
        for (int kc = 0; kc < 2; kc++) {
            short8 wl0 = *(const short8*)(Wp_lin + ((long)((wv * 4 + tnp * 2 + 0) * 2 + kc) << 9) + lane * 8);
            short8 wl1 = *(const short8*)(Wp_lin + ((long)((wv * 4 + tnp * 2 + 1) * 2 + kc) << 9) + lane * 8);
#pragma unroll
            for (int r = 0; r < 2; r++) {
                accl[r][0] = __builtin_amdgcn_mfma_f32_16x16x32_bf16(xsf[r][kc], wl0, accl[r][0], 0, 0, 0);
                accl[r][1] = __builtin_amdgcn_mfma_f32_16x16x32_bf16(xsf[r][kc], wl1, accl[r][1], 0, 0, 0);
            }
        }
        // B2: logits = z @ W_gate, K=256, kc-outer, A from LDS
        f32x4 acc1[2][2];
#pragma unroll
        for (int r = 0; r < 2; r++)
#pragma unroll
            for (int h = 0; h < 2; h++) acc1[r][h] = (f32x4){0.f, 0.f, 0.f, 0.f};
#pragma unroll
        for (int kc = 0; kc < 8; kc++) {
            short8 w0 = *(const short8*)(Wp_gate + ((long)((wv * 4 + tnp * 2 + 0) * 8 + kc) << 9) + lane * 8);
            short8 w1 = *(const short8*)(Wp_gate + ((long)((wv * 4 + tnp * 2 + 1) * 8 + kc) << 9) + lane * 8);
#pragma unroll
            for (int r = 0; r < 2; r++) {
                short8 af = *(const short8*)(&z_lds[(r * 16 + l15) * ZSTR + kc * 32 + quad * 8]);
                acc1[r][0] = __builtin_amdgcn_mfma_f32_16x16x32_bf16(af, w0, acc1[r][0], 0, 0, 0);
                acc1[r][1] = __builtin_amdgcn_mfma_f32_16x16x32_bf16(af, w1, acc1[r][1], 0, 0, 0);
            }
        }
        // epilogue: o = relu((1-g)*xl + g*z), packed bf16 into o_pk (z_lds write deferred)
#pragma unroll
        for (int h = 0; h < 2; h++) {
            int tn = tnp * 2 + h;
            int col = wv * 64 + tn * 16 + l15;
#pragma unroll
            for (int r = 0; r < 2; r++) {
                unsigned short op4[4];
#pragma unroll
                for (int r2 = 0; r2 < 4; r2++) {
                    int rl = r * 16 + quad * 4 + r2;
                    float g = fast_sigmoid(acc1[r][h][r2] + bgc[tn]);
                    float zv = bf2f(z_lds[rl * ZSTR + col]);
                    float xv = accl[r][h][r2] + blc[tn];
                    float o = fmaxf((1.f - g) * xv + g * zv, 0.f);
                    op4[r2] = f2bf(o);
                }
                o_pk[r][tn].x = (unsigned int)op4[0] | ((unsigned int)op4[1] << 16);
                o_pk[r][tn].y = (unsigned int)op4[2] | ((unsigned int)op4[3] << 16);
            }
        }
    }
    __syncthreads();   // all z_lds reads (B2 + epilogue) complete before o write-back

    // ---- write o back into z_lds (in place) ----
#pragma unroll
    for (int r = 0; r < 2; r++)
#pragma unroll
        for (int tn = 0; tn < 4; tn++) {
            int col = wv * 64 + tn * 16 + l15;
            int rl = r * 16 + quad * 4;
            z_lds[(rl + 0) * ZSTR + col] = (unsigned short)(o_pk[r][tn].x & 0xFFFF);
            z_lds[(rl + 1) * ZSTR + col] = (unsigned short)(o_pk[r][tn].x >> 16);
            z_lds[(rl + 2) * ZSTR + col] = (unsigned short)(o_pk[r][tn].y & 0xFFFF);
            z_lds[(rl + 3) * ZSTR + col] = (unsigned short)(o_pk[r][tn].y >> 16);
        }
    __syncthreads();

    // ---- coalesced tile store: 4 x dwordx4 per thread (32x256 tile) ----
#pragma unroll
    for (int it = 0; it < 4; it++) {
        int g = it * 2048 + tid * 8;       // shorts within 32x256 tile
        int row = g >> 8;
        int col = g & 255;
        short8 v = *(const short8*)(&z_lds[row * ZSTR + col]);
        *(short8*)(out_pre + (long)(blockIdx.x * 32 + row) * D_HID + col) = v;
    }
    (void)n;
}

// ---------------- BN stats: column-reduce out_pre (bf16) -> colsum/colsumsq -------------
__global__ __launch_bounds__(256) void k_stats(const unsigned short* __restrict__ op,
                        float* __restrict__ colsum, float* __restrict__ colsumsq, int n) {
    __shared__ float reds[4][32][8];
    __shared__ float redq[4][32][8];
    int tid = threadIdx.x;
    int wv = tid >> 6;
    int lane = tid & 63;
    int cg = tid & 31;        // column group: cols cg*8 .. cg*8+7
    int rb = tid >> 5;        // row offset 0..7
    float ls[8], lq[8];
#pragma unroll
    for (int j = 0; j < 8; j++) { ls[j] = 0.f; lq[j] = 0.f; }
    for (int row = blockIdx.x * 8 + rb; row < n; row += SB * 8) {
        short8 v = *(const short8*)(op + (long)row * D_HID + cg * 8);
#pragma unroll
        for (int j = 0; j < 8; j++) {
            float f = bf2f((unsigned short)v[j]);
            ls[j] += f;
            lq[j] += f * f;
        }
    }
    // lanes L and L^32 share cg -> pair-reduce within wave
#pragma unroll
    for (int j = 0; j < 8; j++) {
        ls[j] += __shfl_xor(ls[j], 32);
        lq[j] += __shfl_xor(lq[j], 32);
    }
    if (lane < 32) {
#pragma unroll
        for (int j = 0; j < 8; j++) {
            reds[wv][cg][j] = ls[j];
            redq[wv][cg][j] = lq[j];
        }
    }
    __syncthreads();
    if (wv == 0 && lane < 32) {
#pragma unroll
        for (int j = 0; j < 8; j++) {
            float s = reds[0][cg][j] + reds[1][cg][j] + reds[2][cg][j] + reds[3][cg][j];
            float q = redq[0][cg][j] + redq[1][cg][j] + redq[2][cg][j] + redq[3][cg][j];
            atomicAdd(&colsum[cg * 8 + j], s);
            atomicAdd(&colsumsq[cg * 8 + j], q);
        }
    }
}

// ---------------- BN apply (finalize folded in): bf16 in -> fp32 out, 8 elems/thread ----
__global__ __launch_bounds__(256) void k_bn_apply(const unsigned short* __restrict__ op,
                           float* __restrict__ out,
                           const float* __restrict__ colsum, const float* __restrict__ colsumsq,
                           const float* __restrict__ gamma, const float* __restrict__ beta,
                           int n, int total8) {
    int i8 = blockIdx.x * blockDim.x + threadIdx.x;
    if (i8 >= total8) return;
    long idx = (long)i8 * 8;
    short8 p = *(const short8*)(op + idx);
    int c = (int)(idx & (D_HID - 1));
    float inv_n = 1.0f / (float)n;
    float vo[8];
#pragma unroll
    for (int j = 0; j < 8; j++) {
        float mu = colsum[c + j] * inv_n;
        float var = colsumsq[c + j] * inv_n - mu * mu;
        float sc = gamma[c + j] * rsqrtf(var + BN_EPS);
        vo[j] = bf2f((unsigned short)p[j]) * sc + (beta[c + j] - mu * sc);
    }
    float4v v0 = {vo[0], vo[1], vo[2], vo[3]};
    float4v v1 = {vo[4], vo[5], vo[6], vo[7]};
    __builtin_nontemporal_store(v0, (float4v*)(out + idx));      // write-once output
    __builtin_nontemporal_store(v1, (float4v*)(out + idx + 4));
}

extern "C" void kernel_launch(void* const* d_in, const int* in_sizes, int n_in,
                              void* d_out, int out_size, void* d_ws, size_t ws_size,
                              hipStream_t stream) {
    const float* xs     = (const float*)d_in[0];
    const int*   eidx   = (const int*)d_in[1];
    const float* W_gcn  = (const float*)d_in[2];
    const float* b_gcn  = (const float*)d_in[3];
    const float* W_lin  = (const float*)d_in[4];
    const float* b_lin  = (const float*)d_in[5];
    const float* W_gate = (const float*)d_in[6];
    const float* b_gate = (const float*)d_in[7];
    const float* gamma  = (const float*)d_in[8];
    const float* beta   = (const float*)d_in[9];
    float* out = (float*)d_out;

    const int n = in_sizes[0] / D_IN;   // 50000
    const int E = in_sizes[1] / 2;      // 800000
    const int npad = (n + 63) & ~63;
    const int nbins = (n + 255) >> 8;   // 196
    const long PS = (long)(n + 1) * 32; // xscaled plane stride (shorts)

    // workspace layout (512B aligned). Zero span: bincur + colsum + colsumsq (~3KB).
    char* ws = (char*)d_ws;
    size_t off = 0;
    auto alloc = [&](size_t bytes) {
        char* p = ws + off;
        off += (bytes + 511) & ~(size_t)511;
        return p;
    };
    size_t zero_begin = off;
    int*            bincur   = (int*)alloc(256 * 4);
    float*          colsum   = (float*)alloc(D_HID * 4);
    float*          colsumsq = (float*)alloc(D_HID * 4);
    size_t zero_end = off;
    int*            cnt      = (int*)alloc((size_t)n * 4);                    // written wholesale
    unsigned int*   binbuf   = (unsigned int*)alloc((size_t)nbins * BINCAP * 4);
    unsigned short* csr      = (unsigned short*)alloc((size_t)n * BCAP * 2);  // bucket CSR
    float*          dinv     = (float*)alloc((size_t)n * 4);
    unsigned short* xpl      = (unsigned short*)alloc((size_t)2 * PS * 2);    // 2 planes +sentinel
    unsigned short* xs_p     = (unsigned short*)alloc((size_t)npad * D_IN * 2);
    unsigned short* agg_p    = (unsigned short*)alloc((size_t)npad * D_IN * 2);
    unsigned short* out_pre  = (unsigned short*)alloc((size_t)npad * D_HID * 2);
    unsigned short* Wp_gcn   = (unsigned short*)alloc((size_t)D_IN * D_HID * 2);
    unsigned short* Wp_lin   = (unsigned short*)alloc((size_t)D_IN * D_HID * 2);
    unsigned short* Wp_gate  = (unsigned short*)alloc((size_t)D_HID * D_HID * 2);
    (void)ws_size;

    const int B = 256;

    // 0. zero bin cursors + BN accumulators (single small memset node)
    hipMemsetAsync(ws + zero_begin, 0, zero_end - zero_begin, stream);
    // 1. pack weights + phase-A edge binning (chunked contiguous writes)
    k_pre<<<384, B, 0, stream>>>(W_gcn, W_lin, W_gate, Wp_gcn, Wp_lin, Wp_gate,
                                 eidx, bincur, binbuf, E);
    // 2. phase-B: per-bin CSR built in LDS, written coalesced (+ true degrees)
    k_binfill<<<nbins, B, 0, stream>>>(binbuf, bincur, csr, cnt, n);
    // 3. dinv + bf16 feature prep into two planes + sentinel
    k_prep<<<(n * 8 + 8 + B - 1) / B, B, 0, stream>>>(xs, cnt, dinv, xpl, xs_p, n);
    // 4. gather aggregation: one phased dispatch per 3.2MB feature plane (L2-resident)
    k_gather<<<(n + 3) / 4, B, 0, stream>>>(csr, cnt, xpl,          dinv, agg_p, n, 0);
    k_gather<<<(n + 3) / 4, B, 0, stream>>>(csr, cnt, xpl + PS,     dinv, agg_p, n, 1);
    // 5. fused GEMMs + epilogue (32-row blocks, reg-prefetched A, 4 waves/SIMD)
    k_fused<<<npad / 32, B, 0, stream>>>(agg_p, xs_p, Wp_gcn, Wp_lin, Wp_gate,
                                         b_gcn, b_gate, b_lin, out_pre, n);
    // 6. BN column stats from out_pre
    k_stats<<<SB, B, 0, stream>>>(out_pre, colsum, colsumsq, n);
    // 7. BN apply (finalize folded in; bf16 -> fp32)
    {
        int total8 = n * D_HID / 8;
        k_bn_apply<<<(total8 + B - 1) / B, B, 0, stream>>>(out_pre, out, colsum, colsumsq,
                                                           gamma, beta, n, total8);
    }
}

// Round 8
// 213.989 us; speedup vs baseline: 1.0832x; 1.0832x over previous
//
#include <hip/hip_runtime.h>
#include <math.h>

#define NN 50000
#define NE 800000
#define D_IN 64
#define D_HID 256
#define BN_EPS 1e-5f
#define ZSTR 264   // LDS tile row stride in shorts (+8 pad: 16B-aligned rows, spread banks)
#define SB 128     // k_stats grid blocks
#define BCAP 64    // CSR bucket capacity per node (Poisson(16): P(deg>=64) ~ 1e-18)
#define BINCAP 8192 // edges per 256-node bin (mean 4081, 64 sigma headroom)

typedef __attribute__((ext_vector_type(8))) short short8;
typedef __attribute__((ext_vector_type(4))) float f32x4;
typedef __attribute__((ext_vector_type(4))) int int4v;      // ext-vector: nontemporal-legal
typedef __attribute__((ext_vector_type(4))) float float4v;  // ext-vector: nontemporal-legal

static __device__ __forceinline__ unsigned short f2bf(float f) {
    unsigned int u = __builtin_bit_cast(unsigned int, f);
    u += 0x7FFFu + ((u >> 16) & 1u);   // round-to-nearest-even
    return (unsigned short)(u >> 16);
}
static __device__ __forceinline__ float bf2f(unsigned short s) {
    unsigned int u = ((unsigned int)s) << 16;
    return __builtin_bit_cast(float, u);
}
// fast sigmoid: rcp(1+e^-x). Saturates cleanly at +/-inf, no NaN.
static __device__ __forceinline__ float fast_sigmoid(float x) {
    return __builtin_amdgcn_rcpf(1.0f + __expf(-x));
}
// fast tanh: 1 - 2*rcp(e^{2x}+1). Saturates cleanly, no NaN.
static __device__ __forceinline__ float fast_tanh(float x) {
    return 1.0f - 2.0f * __builtin_amdgcn_rcpf(__expf(2.0f * x) + 1.0f);
}

// A-frag-linear address for element (row i, feature k):
// ((i>>4)*2 + (k>>5))*512 + (((k>>3)&3)*16 + (i&15))*8 + (k&7)
static __device__ __forceinline__ long a_addr(int i, int k) {
    return ((long)((i >> 4) * 2 + (k >> 5)) << 9) + ((((k >> 3) & 3) * 16 + (i & 15)) << 3) + (k & 7);
}

// ---------------- pre: pack weights + PHASE-A edge binning ------------------------------
// Bin edges by dst>>8 into contiguous per-bin chunks (LDS count -> one global cursor
// atomicAdd per (block,bin) -> ~84B contiguous chunk writes). eidx loads non-temporal
// (read-once stream; don't churn L2).
__global__ __launch_bounds__(256) void k_pre(const float* __restrict__ W_gcn,
                      const float* __restrict__ W_lin, const float* __restrict__ W_gate,
                      unsigned short* __restrict__ Wp_gcn, unsigned short* __restrict__ Wp_lin,
                      unsigned short* __restrict__ Wp_gate,
                      const int* __restrict__ eidx, int* __restrict__ bincur,
                      unsigned int* __restrict__ binbuf, int E) {
    int idx = blockIdx.x * blockDim.x + threadIdx.x;
    if (idx < 98304) {
        const float* W;
        unsigned short* Wp;
        int KC, o;
        if (idx < 16384)      { W = W_gcn;  Wp = Wp_gcn;  KC = 2; o = idx; }
        else if (idx < 32768) { W = W_lin;  Wp = Wp_lin;  KC = 2; o = idx - 16384; }
        else                  { W = W_gate; Wp = Wp_gate; KC = 8; o = idx - 32768; }
        int j = o & 7;
        int lane = (o >> 3) & 63;
        int rest = o >> 9;
        int kc = rest % KC;
        int ct = rest / KC;
        int col = ct * 16 + (lane & 15);
        int k = kc * 32 + (lane >> 4) * 8 + j;
        Wp[o] = f2bf(W[k * D_HID + col]);
    }

    // ---- phase A binning: blocks 0..nbb-1, 4096 edges each ----
    int b = blockIdx.x;
    int t = threadIdx.x;
    int nbb = (E + 4095) >> 12;
    if (b < nbb) {
        __shared__ int bcnt[256];
        __shared__ int gbase[256];
        bcnt[t] = 0;
        __syncthreads();
        unsigned int pair[4][4];
        int bin[4][4], lr[4][4];
        bool val[4];
#pragma unroll
        for (int c = 0; c < 4; c++) {
            int e0 = b * 4096 + c * 1024 + t * 4;
            val[c] = e0 < E;
            if (val[c]) {
                int4v s = __builtin_nontemporal_load((const int4v*)(eidx + e0));
                int4v d = __builtin_nontemporal_load((const int4v*)(eidx + E + e0));
                int ss[4] = {s[0], s[1], s[2], s[3]};
                int dd[4] = {d[0], d[1], d[2], d[3]};
#pragma unroll
                for (int j = 0; j < 4; j++) {
                    int bi = dd[j] >> 8;
                    bin[c][j] = bi;
                    pair[c][j] = ((unsigned int)(dd[j] & 255) << 16) | (unsigned int)ss[j];
                    lr[c][j] = atomicAdd(&bcnt[bi], 1);
                }
            }
        }
        __syncthreads();
        if (bcnt[t] > 0) gbase[t] = atomicAdd(&bincur[t], bcnt[t]);
        __syncthreads();
#pragma unroll
        for (int c = 0; c < 4; c++)
            if (val[c]) {
#pragma unroll
                for (int j = 0; j < 4; j++) {
                    int slot = gbase[bin[c][j]] + lr[c][j];
                    if (slot < BINCAP)
                        binbuf[((long)bin[c][j] << 13) + slot] = pair[c][j];
                }
            }
    }
}

// ---------------- binfill: per-bin CSR in LDS + ABSORBED feature prep -------------------
// Round-16: k_prep merged in. The block already holds every one of its 256 nodes'
// degrees in LDS (lcnt) -> dinv/xscaled packing needs no cnt round-trip and no extra
// dispatch. All global writes (csr, cnt, xscaled, xs_p) fully coalesced.
__global__ __launch_bounds__(256) void k_binfill(const unsigned int* __restrict__ binbuf,
                      const int* __restrict__ bincur, const float* __restrict__ xs,
                      unsigned short* __restrict__ csr, int* __restrict__ cnt,
                      float* __restrict__ dinv, unsigned short* __restrict__ xscaled,
                      unsigned short* __restrict__ xs_p, int n) {
    __shared__ unsigned short buck[256 * BCAP];   // 32KB
    __shared__ int lcnt[256];
    int b = blockIdx.x;
    int t = threadIdx.x;
    lcnt[t] = 0;
    __syncthreads();
    int tot = bincur[b];
    tot = tot < BINCAP ? tot : BINCAP;
    for (int i = t; i < tot; i += 256) {
        unsigned int p = binbuf[((long)b << 13) + i];
        int dl = p >> 16;
        int src = p & 0xFFFF;
        int r = atomicAdd(&lcnt[dl], 1);
        if (r < BCAP) buck[dl * BCAP + r] = (unsigned short)src;
    }
    __syncthreads();
    int node0 = b << 8;
    if (node0 + t < n) cnt[node0 + t] = lcnt[t];   // true degree (gather clamps to BCAP)
    // csr write: 2048 short8 rows -> 8 per thread, fully coalesced
#pragma unroll
    for (int v = 0; v < 8; v++) {
        int e = (v * 256 + t) * 8;      // short index into buck
        int node = e >> 6;
        if (node0 + node < n)
            *(short8*)(csr + ((long)(node0 + node) << 6) + (e & 63)) = *(const short8*)(&buck[e]);
    }
    // feature packing (ex-k_prep): 2048 octet-items -> 8 per thread, coalesced 32B reads
#pragma unroll
    for (int v = 0; v < 8; v++) {
        int item = v * 256 + t;
        int nl = item >> 3;
        int sub = item & 7;
        int node = node0 + nl;
        if (node < n) {
            float dv = rsqrtf(1.0f + (float)lcnt[nl]);
            if (sub == 0) dinv[node] = dv;
            const float* p = xs + (long)node * D_IN + sub * 8;
            float4v f0 = __builtin_nontemporal_load((const float4v*)p);
            float4v f1 = __builtin_nontemporal_load((const float4v*)(p + 4));
            float vals[8] = {f0[0], f0[1], f0[2], f0[3], f1[0], f1[1], f1[2], f1[3]};
            short8 xsc, xsb;
#pragma unroll
            for (int j = 0; j < 8; j++) {
                xsc[j] = (short)f2bf(vals[j] * dv);
                xsb[j] = (short)f2bf(vals[j]);
            }
            *(short8*)(xscaled + (long)node * D_IN + sub * 8) = xsc;
            *(short8*)(xs_p + a_addr(node, sub * 8)) = xsb;
        } else if (node == n) {         // zero sentinel row (gather tail clamp target)
            short8 zv = (short8){0, 0, 0, 0, 0, 0, 0, 0};
            *(short8*)(xscaled + (long)n * D_IN + sub * 8) = zv;
        }
    }
}

// ---------------- gather aggregation: wave per node, 8 rows x 16B/lane per round --------
// Round-16 REVERT of the plane-split (r7: +17us): gather is BW/request-bound (12500
// blocks of TLP hide L3 latency); the split kept the same 16B-request count while
// doubling the csr stream and adding a dispatch. Single pass, 128B rows, cached csr.
__global__ __launch_bounds__(256) void k_gather(const unsigned short* __restrict__ csr,
                                                const int* __restrict__ cnt,
                                                const unsigned short* __restrict__ xscaled,
                                                const float* __restrict__ dinv,
                                                unsigned short* __restrict__ agg_p, int n) {
    int wv = threadIdx.x >> 6;
    int lane = threadIdx.x & 63;
    int sub = lane & 7;
    int grp = lane >> 3;
    int i = blockIdx.x * 4 + wv;
    if (i >= n) return;
    int c = cnt[i];
    c = c < BCAP ? c : BCAP;            // bucket clamp (never hit for this data)
    float acc[8];
#pragma unroll
    for (int j = 0; j < 8; j++) acc[j] = 0.f;
    int idxv = (lane < c) ? (int)csr[((long)i << 6) + lane] : 0;
    int tmax = (c + 7) >> 3;            // wave-uniform trip count
    for (int t = 0; t < tmax; t++) {
        int e = t * 8 + grp;
        int rowv = __shfl(idxv, e);
        int row = (e < c) ? rowv : n;   // clamp tail to zero sentinel row
        short8 v = *(const short8*)(xscaled + (long)row * D_IN + sub * 8);
#pragma unroll
        for (int j = 0; j < 8; j++) acc[j] += bf2f((unsigned short)v[j]);
    }
#pragma unroll
    for (int d = 8; d <= 32; d <<= 1)
#pragma unroll
        for (int j = 0; j < 8; j++) acc[j] += __shfl_xor(acc[j], d);
    if (grp == 0) {
        float dv = dinv[i];
        short8 sv = *(const short8*)(xscaled + (long)i * D_IN + sub * 8);  // self loop
        short8 o;
#pragma unroll
        for (int j = 0; j < 8; j++)
            o[j] = (short)f2bf((acc[j] + bf2f((unsigned short)sv[j])) * dv);
        *(short8*)(agg_p + a_addr(i, sub * 8)) = o;
    }
}

// ---------------- fused v6: TLP-focused -------------------------------------------------
//   (a) 32-row blocks: grid 1564, LDS 16.9 KB
//   (b) __launch_bounds__(256,4): VGPR cap 128 -> 4 waves/SIMD
//   (c) A-tiles (agg, xs) prefetched into registers at kernel entry
__global__ __launch_bounds__(256, 4) void k_fused(const unsigned short* __restrict__ agg_p,
                        const unsigned short* __restrict__ xs_p,
                        const unsigned short* __restrict__ Wp_gcn,
                        const unsigned short* __restrict__ Wp_lin,
                        const unsigned short* __restrict__ Wp_gate,
                        const float* __restrict__ b_gcn,
                        const float* __restrict__ bg,
                        const float* __restrict__ bl,
                        unsigned short* __restrict__ out_pre,  // [npad][256]
                        int n) {
    __shared__ unsigned short z_lds[32 * ZSTR];   // 16.9 KB (z, then o in-place)

    int tid = threadIdx.x;
    int wv = tid >> 6;
    int lane = tid & 63;
    int l15 = lane & 15;
    int quad = lane >> 4;
    int rt0 = blockIdx.x * 2;           // 2 row-tiles of 16 per block

    // ---- prefetch both A-operand tiles into registers (issued before anything else) ----
    short8 aggf[2][2], xsf[2][2];
#pragma unroll
    for (int r = 0; r < 2; r++)
#pragma unroll
        for (int kc = 0; kc < 2; kc++) {
            aggf[r][kc] = *(const short8*)(agg_p + ((long)((rt0 + r) * 2 + kc) << 9) + lane * 8);
            xsf[r][kc]  = *(const short8*)(xs_p  + ((long)((rt0 + r) * 2 + kc) << 9) + lane * 8);
        }

    // ---- phase A: z = tanh(agg @ W_gcn + b), K=64 ----
    {
        short8 wg[2][4];
#pragma unroll
        for (int kc = 0; kc < 2; kc++)
#pragma unroll
            for (int tn = 0; tn < 4; tn++)
                wg[kc][tn] = *(const short8*)(Wp_gcn + ((long)((wv * 4 + tn) * 2 + kc) << 9) + lane * 8);
        float bias[4];
#pragma unroll
        for (int tn = 0; tn < 4; tn++) bias[tn] = b_gcn[wv * 64 + tn * 16 + l15];
#pragma unroll
        for (int r = 0; r < 2; r++) {
            f32x4 accz[4];
#pragma unroll
            for (int c = 0; c < 4; c++) accz[c] = (f32x4){0.f, 0.f, 0.f, 0.f};
#pragma unroll
            for (int kc = 0; kc < 2; kc++)
#pragma unroll
                for (int tn = 0; tn < 4; tn++)
                    accz[tn] = __builtin_amdgcn_mfma_f32_16x16x32_bf16(aggf[r][kc], wg[kc][tn], accz[tn], 0, 0, 0);
#pragma unroll
            for (int tn = 0; tn < 4; tn++) {
                int col = wv * 64 + tn * 16 + l15;
#pragma unroll
                for (int r2 = 0; r2 < 4; r2++)
                    z_lds[(r * 16 + quad * 4 + r2) * ZSTR + col] = f2bf(fast_tanh(accz[tn][r2] + bias[tn]));
            }
        }
    }
    __syncthreads();

    // ---- phase B per tn-pair: xl GEMM (A in regs) -> gate GEMM -> epilogue ----
    uint2 o_pk[2][4];
    float bgc[4], blc[4];
#pragma unroll
    for (int tn = 0; tn < 4; tn++) {
        int col = wv * 64 + tn * 16 + l15;
        bgc[tn] = bg[col];
        blc[tn] = bl[col];
    }
#pragma unroll
    for (int tnp = 0; tnp < 2; tnp++) {
        // B1: xl = xs @ W_lin, K=64, A-frags already in registers
        f32x4 accl[2][2];
#pragma unroll
        for (int r = 0; r < 2; r++)
#pragma unroll
            for (int h = 0; h < 2; h++) accl[r][h] = (f32x4){0.f, 0.f, 0.f, 0.f};
#pragma unroll
        for (int kc = 0; kc < 2; kc++) {
            short8 wl0 = *(const short8*)(Wp_lin + ((long)((wv * 4 + tnp * 2 + 0) * 2 + kc) << 9) + lane * 8);
            short8 wl1 = *(const short8*)(Wp_lin + ((long)((wv * 4 + tnp * 2 + 1) * 2 + kc) << 9) + lane * 8);
#pragma unroll
            for (int r = 0; r < 2; r++) {
                accl[r][0] = __builtin_amdgcn_mfma_f32_16x16x32_bf16(xsf[r][kc], wl0, accl[r][0], 0, 0, 0);
                accl[r][1] = __builtin_amdgcn_mfma_f32_16x16x32_bf16(xsf[r][kc], wl1, accl[r][1], 0, 0, 0);
            }
        }
        // B2: logits = z @ W_gate, K=256, kc-outer, A from LDS
        f32x4 acc1[2][2];
#pragma unroll
        for (int r = 0; r < 2; r++)
#pragma unroll
            for (int h = 0; h < 2; h++) acc1[r][h] = (f32x4){0.f, 0.f, 0.f, 0.f};
#pragma unroll
        for (int kc = 0; kc < 8; kc++) {
            short8 w0 = *(const short8*)(Wp_gate + ((long)((wv * 4 + tnp * 2 + 0) * 8 + kc) << 9) + lane * 8);
            short8 w1 = *(const short8*)(Wp_gate + ((long)((wv * 4 + tnp * 2 + 1) * 8 + kc) << 9) + lane * 8);
#pragma unroll
            for (int r = 0; r < 2; r++) {
                short8 af = *(const short8*)(&z_lds[(r * 16 + l15) * ZSTR + kc * 32 + quad * 8]);
                acc1[r][0] = __builtin_amdgcn_mfma_f32_16x16x32_bf16(af, w0, acc1[r][0], 0, 0, 0);
                acc1[r][1] = __builtin_amdgcn_mfma_f32_16x16x32_bf16(af, w1, acc1[r][1], 0, 0, 0);
            }
        }
        // epilogue: o = relu((1-g)*xl + g*z), packed bf16 into o_pk (z_lds write deferred)
#pragma unroll
        for (int h = 0; h < 2; h++) {
            int tn = tnp * 2 + h;
            int col = wv * 64 + tn * 16 + l15;
#pragma unroll
            for (int r = 0; r < 2; r++) {
                unsigned short op4[4];
#pragma unroll
                for (int r2 = 0; r2 < 4; r2++) {
                    int rl = r * 16 + quad * 4 + r2;
                    float g = fast_sigmoid(acc1[r][h][r2] + bgc[tn]);
                    float zv = bf2f(z_lds[rl * ZSTR + col]);
                    float xv = accl[r][h][r2] + blc[tn];
                    float o = fmaxf((1.f - g) * xv + g * zv, 0.f);
                    op4[r2] = f2bf(o);
                }
                o_pk[r][tn].x = (unsigned int)op4[0] | ((unsigned int)op4[1] << 16);
                o_pk[r][tn].y = (unsigned int)op4[2] | ((unsigned int)op4[3] << 16);
            }
        }
    }
    __syncthreads();   // all z_lds reads (B2 + epilogue) complete before o write-back

    // ---- write o back into z_lds (in place) ----
#pragma unroll
    for (int r = 0; r < 2; r++)
#pragma unroll
        for (int tn = 0; tn < 4; tn++) {
            int col = wv * 64 + tn * 16 + l15;
            int rl = r * 16 + quad * 4;
            z_lds[(rl + 0) * ZSTR + col] = (unsigned short)(o_pk[r][tn].x & 0xFFFF);
            z_lds[(rl + 1) * ZSTR + col] = (unsigned short)(o_pk[r][tn].x >> 16);
            z_lds[(rl + 2) * ZSTR + col] = (unsigned short)(o_pk[r][tn].y & 0xFFFF);
            z_lds[(rl + 3) * ZSTR + col] = (unsigned short)(o_pk[r][tn].y >> 16);
        }
    __syncthreads();

    // ---- coalesced tile store: 4 x dwordx4 per thread (32x256 tile) ----
#pragma unroll
    for (int it = 0; it < 4; it++) {
        int g = it * 2048 + tid * 8;       // shorts within 32x256 tile
        int row = g >> 8;
        int col = g & 255;
        short8 v = *(const short8*)(&z_lds[row * ZSTR + col]);
        *(short8*)(out_pre + (long)(blockIdx.x * 32 + row) * D_HID + col) = v;
    }
    (void)n;
}

// ---------------- BN stats: column-reduce out_pre (bf16) -> colsum/colsumsq -------------
__global__ __launch_bounds__(256) void k_stats(const unsigned short* __restrict__ op,
                        float* __restrict__ colsum, float* __restrict__ colsumsq, int n) {
    __shared__ float reds[4][32][8];
    __shared__ float redq[4][32][8];
    int tid = threadIdx.x;
    int wv = tid >> 6;
    int lane = tid & 63;
    int cg = tid & 31;        // column group: cols cg*8 .. cg*8+7
    int rb = tid >> 5;        // row offset 0..7
    float ls[8], lq[8];
#pragma unroll
    for (int j = 0; j < 8; j++) { ls[j] = 0.f; lq[j] = 0.f; }
    for (int row = blockIdx.x * 8 + rb; row < n; row += SB * 8) {
        short8 v = *(const short8*)(op + (long)row * D_HID + cg * 8);
#pragma unroll
        for (int j = 0; j < 8; j++) {
            float f = bf2f((unsigned short)v[j]);
            ls[j] += f;
            lq[j] += f * f;
        }
    }
    // lanes L and L^32 share cg -> pair-reduce within wave
#pragma unroll
    for (int j = 0; j < 8; j++) {
        ls[j] += __shfl_xor(ls[j], 32);
        lq[j] += __shfl_xor(lq[j], 32);
    }
    if (lane < 32) {
#pragma unroll
        for (int j = 0; j < 8; j++) {
            reds[wv][cg][j] = ls[j];
            redq[wv][cg][j] = lq[j];
        }
    }
    __syncthreads();
    if (wv == 0 && lane < 32) {
#pragma unroll
        for (int j = 0; j < 8; j++) {
            float s = reds[0][cg][j] + reds[1][cg][j] + reds[2][cg][j] + reds[3][cg][j];
            float q = redq[0][cg][j] + redq[1][cg][j] + redq[2][cg][j] + redq[3][cg][j];
            atomicAdd(&colsum[cg * 8 + j], s);
            atomicAdd(&colsumsq[cg * 8 + j], q);
        }
    }
}

// ---------------- BN apply (finalize folded in): bf16 in -> fp32 out, 8 elems/thread ----
__global__ __launch_bounds__(256) void k_bn_apply(const unsigned short* __restrict__ op,
                           float* __restrict__ out,
                           const float* __restrict__ colsum, const float* __restrict__ colsumsq,
                           const float* __restrict__ gamma, const float* __restrict__ beta,
                           int n, int total8) {
    int i8 = blockIdx.x * blockDim.x + threadIdx.x;
    if (i8 >= total8) return;
    long idx = (long)i8 * 8;
    short8 p = *(const short8*)(op + idx);
    int c = (int)(idx & (D_HID - 1));
    float inv_n = 1.0f / (float)n;
    float vo[8];
#pragma unroll
    for (int j = 0; j < 8; j++) {
        float mu = colsum[c + j] * inv_n;
        float var = colsumsq[c + j] * inv_n - mu * mu;
        float sc = gamma[c + j] * rsqrtf(var + BN_EPS);
        vo[j] = bf2f((unsigned short)p[j]) * sc + (beta[c + j] - mu * sc);
    }
    float4v v0 = {vo[0], vo[1], vo[2], vo[3]};
    float4v v1 = {vo[4], vo[5], vo[6], vo[7]};
    __builtin_nontemporal_store(v0, (float4v*)(out + idx));      // write-once output
    __builtin_nontemporal_store(v1, (float4v*)(out + idx + 4));
}

extern "C" void kernel_launch(void* const* d_in, const int* in_sizes, int n_in,
                              void* d_out, int out_size, void* d_ws, size_t ws_size,
                              hipStream_t stream) {
    const float* xs     = (const float*)d_in[0];
    const int*   eidx   = (const int*)d_in[1];
    const float* W_gcn  = (const float*)d_in[2];
    const float* b_gcn  = (const float*)d_in[3];
    const float* W_lin  = (const float*)d_in[4];
    const float* b_lin  = (const float*)d_in[5];
    const float* W_gate = (const float*)d_in[6];
    const float* b_gate = (const float*)d_in[7];
    const float* gamma  = (const float*)d_in[8];
    const float* beta   = (const float*)d_in[9];
    float* out = (float*)d_out;

    const int n = in_sizes[0] / D_IN;   // 50000
    const int E = in_sizes[1] / 2;      // 800000
    const int npad = (n + 63) & ~63;
    const int nbins = (n + 255) >> 8;   // 196 (covers sentinel: n>>8 < nbins since 256∤n)

    // workspace layout (512B aligned). Zero span: bincur + colsum + colsumsq (~3KB).
    char* ws = (char*)d_ws;
    size_t off = 0;
    auto alloc = [&](size_t bytes) {
        char* p = ws + off;
        off += (bytes + 511) & ~(size_t)511;
        return p;
    };
    size_t zero_begin = off;
    int*            bincur   = (int*)alloc(256 * 4);
    float*          colsum   = (float*)alloc(D_HID * 4);
    float*          colsumsq = (float*)alloc(D_HID * 4);
    size_t zero_end = off;
    int*            cnt      = (int*)alloc((size_t)n * 4);                    // written wholesale
    unsigned int*   binbuf   = (unsigned int*)alloc((size_t)nbins * BINCAP * 4);
    unsigned short* csr      = (unsigned short*)alloc((size_t)n * BCAP * 2);  // bucket CSR
    float*          dinv     = (float*)alloc((size_t)n * 4);
    unsigned short* xscaled  = (unsigned short*)alloc((size_t)(n + 1) * D_IN * 2);  // +1 zero row
    unsigned short* xs_p     = (unsigned short*)alloc((size_t)npad * D_IN * 2);
    unsigned short* agg_p    = (unsigned short*)alloc((size_t)npad * D_IN * 2);
    unsigned short* out_pre  = (unsigned short*)alloc((size_t)npad * D_HID * 2);
    unsigned short* Wp_gcn   = (unsigned short*)alloc((size_t)D_IN * D_HID * 2);
    unsigned short* Wp_lin   = (unsigned short*)alloc((size_t)D_IN * D_HID * 2);
    unsigned short* Wp_gate  = (unsigned short*)alloc((size_t)D_HID * D_HID * 2);
    (void)ws_size;

    const int B = 256;

    // 0. zero bin cursors + BN accumulators (single small memset node)
    hipMemsetAsync(ws + zero_begin, 0, zero_end - zero_begin, stream);
    // 1. pack weights + phase-A edge binning (chunked contiguous writes)
    k_pre<<<384, B, 0, stream>>>(W_gcn, W_lin, W_gate, Wp_gcn, Wp_lin, Wp_gate,
                                 eidx, bincur, binbuf, E);
    // 2. per-bin CSR in LDS + absorbed feature prep (dinv/xscaled/xs_p/sentinel)
    k_binfill<<<nbins, B, 0, stream>>>(binbuf, bincur, xs, csr, cnt, dinv, xscaled, xs_p, n);
    // 3. gather aggregation (wave per node, single pass, 128B rows)
    k_gather<<<(n + 3) / 4, B, 0, stream>>>(csr, cnt, xscaled, dinv, agg_p, n);
    // 4. fused GEMMs + epilogue (32-row blocks, reg-prefetched A, 4 waves/SIMD)
    k_fused<<<npad / 32, B, 0, stream>>>(agg_p, xs_p, Wp_gcn, Wp_lin, Wp_gate,
                                         b_gcn, b_gate, b_lin, out_pre, n);
    // 5. BN column stats from out_pre
    k_stats<<<SB, B, 0, stream>>>(out_pre, colsum, colsumsq, n);
    // 6. BN apply (finalize folded in; bf16 -> fp32)
    {
        int total8 = n * D_HID / 8;
        k_bn_apply<<<(total8 + B - 1) / B, B, 0, stream>>>(out_pre, out, colsum, colsumsq,
                                                           gamma, beta, n, total8);
    }
}